// Round 6
// baseline (623.598 us; speedup 1.0000x reference)
//
#include <hip/hip_runtime.h>

#define BB 16
#define CC 64
#define NN 65536
#define NBV 4
#define B64 (BB * 64)

// ws layout (fp32 elems):
//   xT     : B*N*C  (268 MB) — pixel-tiled transpose [b][gg=n/256][c][n%256]
//   score  : B*N
//   bval   : 2*B64 | bidx 2*B64 (int) | wpart B*64*64 | sspart B*64

// Initial argmax over score_init (64 blocks/batch x 1024 scores) + zero selectedPos.
// Tie rule everywhere: larger value wins; equal -> smaller index (np.argmax = first max).
__global__ __launch_bounds__(256)
void k_argmax1(const float* __restrict__ sc_in,
               float* __restrict__ bval, int* __restrict__ bidx,
               float* __restrict__ sel_out) {
    int b = blockIdx.y, blk = blockIdx.x, tid = threadIdx.x;
    const float* s = sc_in + (size_t)b * NN + blk * 1024;
    float v = -1e30f; int vi = 0x7fffffff;
    #pragma unroll
    for (int k = 0; k < 4; k++) {
        int idx = k * 256 + tid;               // ascending per thread; strict > keeps earliest
        float xv = s[idx];
        if (xv > v) { v = xv; vi = blk * 1024 + idx; }
    }
    size_t gt = ((size_t)(b * 64 + blk)) * 256 + tid;   // 262144 threads x 4 = B*N
    #pragma unroll
    for (int k = 0; k < 4; k++) sel_out[gt + (size_t)k * 262144] = 0.f;
    __shared__ float sv[256]; __shared__ int si[256];
    sv[tid] = v; si[tid] = vi;
    __syncthreads();
    for (int st = 128; st > 0; st >>= 1) {
        if (tid < st) {
            float ov = sv[tid + st]; int oi = si[tid + st];
            if (ov > sv[tid] || (ov == sv[tid] && oi < si[tid])) { sv[tid] = ov; si[tid] = oi; }
        }
        __syncthreads();
    }
    if (tid == 0) { bval[b * 64 + blk] = sv[0]; bidx[b * 64 + blk] = si[0]; }
}

// One-time layout transform: x[b][c][n] -> xT[b][n/256][c][n%256] (64 KB pixel tiles).
// Reads: 16 KB sequential per block. Writes: 1 KB chunks @ 64 KB stride (strided side paid once).
// grid = (1024, B): blockIdx.x = c*16 + seg, seg covers 4096 px.
__global__ __launch_bounds__(256)
void k_xpose(const float* __restrict__ x, float* __restrict__ xT) {
    int b = blockIdx.y;
    int c = blockIdx.x >> 4, seg = blockIdx.x & 15;
    int tid = threadIdx.x, lane = tid & 63, wv = tid >> 6;
    const float* rp = x + ((size_t)b * 64 + c) * NN + seg * 4096;
    #pragma unroll
    for (int i = 0; i < 4; i++) {
        float4 v = *(const float4*)(rp + i * 1024 + tid * 4);
        int gg = seg * 16 + i * 4 + wv;     // px block of 256
        *(float4*)(xT + (((size_t)b * 256 + gg) * 64 + c) * 256 + lane * 4) = v;
    }
}

// Main per-iteration kernel. grid=(64,B), 256 thr = 4 waves; wave w owns channels 16w..16w+15.
// Reads xT: per group each wave streams 16 consecutive 1 KB rows (16 KB contiguous).
// Per group: partial d2 (float4) -> LDS dbuf, one barrier, cross-wave d2 sum -> sim4,
// 64 acc FMAs. Wave 0: sim/score float4 I/O + fused stage-1 argmax of the NEW score
// for the next iteration (ping-pong bval/bidx).
__global__ __launch_bounds__(256, 2)
void k_iter(const float* __restrict__ xT, const float* __restrict__ x,
            const float* __restrict__ score_in, float* __restrict__ score_out,
            float* __restrict__ bval, int* __restrict__ bidx,
            float* __restrict__ wpart, float* __restrict__ sspart,
            float* __restrict__ sim_out, int iter) {
    int b = blockIdx.y, blk = blockIdx.x, tid = threadIdx.x;
    int lane = tid & 63, wv = tid >> 6;
    __shared__ float raw_s[64];
    __shared__ float4 d2p[2][4][64];

    int rb = (iter & 1) * B64, wb = ((iter & 1) ^ 1) * B64;

    if (tid < 64) {   // finish argmax over 64 block partials, fetch selected pixel's features
        float v = bval[rb + b * 64 + tid]; int vi = bidx[rb + b * 64 + tid];
        #pragma unroll
        for (int off = 32; off >= 1; off >>= 1) {
            float ov = __shfl_down(v, off, 64); int oi = __shfl_down(vi, off, 64);
            if (ov > v || (ov == v && oi < vi)) { v = ov; vi = oi; }
        }
        int ind = __shfl(vi, 0, 64);
        raw_s[tid] = x[((size_t)b * 64 + tid) * NN + ind];
    }
    __syncthreads();

    // wave w's 16 channel rows of tile (blk*4+g) start here
    const float* xtb = xT + (((size_t)b * 256 + blk * 4) * 64 + wv * 16) * 256;
    float raw[16];
    #pragma unroll
    for (int j = 0; j < 16; j++) raw[j] = raw_s[wv * 16 + j];
    float acc[16];
    #pragma unroll
    for (int j = 0; j < 16; j++) acc[j] = 0.f;

    const size_t sb = (size_t)b * NN;
    const size_t simb = (size_t)(b * NBV + iter) * NN;
    const bool w0 = (wv == 0), upd = (iter < 3);

    float ssacc = 0.f, smax = -1e30f; int smaxi = 0;
    float4 sc_next;
    if (w0 && upd) sc_next = *(const float4*)(score_in + sb + blk * 1024 + lane * 4);

    #pragma unroll 1
    for (int g = 0; g < 4; g++) {
        int n0 = blk * 1024 + g * 256 + lane * 4;
        const float* tp = xtb + (size_t)g * 64 * 256;   // this group's tile, our 16 rows
        float4 xv[16];
        #pragma unroll
        for (int j = 0; j < 16; j++) xv[j] = *(const float4*)(tp + j * 256 + lane * 4);
        float4 sc_cur = sc_next;
        if (w0 && upd && g < 3) sc_next = *(const float4*)(score_in + sb + n0 + 256);
        float4 d2 = make_float4(0.f, 0.f, 0.f, 0.f);
        #pragma unroll
        for (int j = 0; j < 16; j++) {
            float r = raw[j];
            float dx = xv[j].x - r, dy = xv[j].y - r, dz = xv[j].z - r, dw = xv[j].w - r;
            d2.x = fmaf(dx, dx, d2.x); d2.y = fmaf(dy, dy, d2.y);
            d2.z = fmaf(dz, dz, d2.z); d2.w = fmaf(dw, dw, d2.w);
        }
        d2p[g & 1][wv][lane] = d2;
        __syncthreads();
        float4 a0 = d2p[g & 1][0][lane], a1 = d2p[g & 1][1][lane];
        float4 a2 = d2p[g & 1][2][lane], a3 = d2p[g & 1][3][lane];
        float4 sim;
        sim.x = expf(-sqrtf(fmaxf((a0.x + a1.x) + (a2.x + a3.x), 1e-12f)) * 0.05f);
        sim.y = expf(-sqrtf(fmaxf((a0.y + a1.y) + (a2.y + a3.y), 1e-12f)) * 0.05f);
        sim.z = expf(-sqrtf(fmaxf((a0.z + a1.z) + (a2.z + a3.z), 1e-12f)) * 0.05f);
        sim.w = expf(-sqrtf(fmaxf((a0.w + a1.w) + (a2.w + a3.w), 1e-12f)) * 0.05f);
        #pragma unroll
        for (int j = 0; j < 16; j++) {
            acc[j] = fmaf(sim.x, xv[j].x, acc[j]);
            acc[j] = fmaf(sim.y, xv[j].y, acc[j]);
            acc[j] = fmaf(sim.z, xv[j].z, acc[j]);
            acc[j] = fmaf(sim.w, xv[j].w, acc[j]);
        }
        if (w0) {
            ssacc += (sim.x + sim.y) + (sim.z + sim.w);
            *(float4*)(sim_out + simb + n0) = sim;
            if (upd) {
                float4 sc;
                sc.x = sc_cur.x * (1.f - sim.x);
                sc.y = sc_cur.y * (1.f - sim.y);
                sc.z = sc_cur.z * (1.f - sim.z);
                sc.w = sc_cur.w * (1.f - sim.w);
                *(float4*)(score_out + sb + n0) = sc;
                // ascending n within lane; strict > = first max
                if (sc.x > smax) { smax = sc.x; smaxi = n0; }
                if (sc.y > smax) { smax = sc.y; smaxi = n0 + 1; }
                if (sc.z > smax) { smax = sc.z; smaxi = n0 + 2; }
                if (sc.w > smax) { smax = sc.w; smaxi = n0 + 3; }
            }
        }
    }

    // per-channel cross-lane reduce; lane 0 writes block partial
    #pragma unroll
    for (int j = 0; j < 16; j++) {
        float v = acc[j];
        #pragma unroll
        for (int off = 32; off >= 1; off >>= 1) v += __shfl_down(v, off, 64);
        if (lane == 0) wpart[(((size_t)b * 64) + blk) * 64 + wv * 16 + j] = v;
    }
    if (w0) {
        float v = ssacc;
        #pragma unroll
        for (int off = 32; off >= 1; off >>= 1) v += __shfl_down(v, off, 64);
        if (lane == 0) sspart[b * 64 + blk] = v;
        if (upd) {
            #pragma unroll
            for (int off = 32; off >= 1; off >>= 1) {
                float ov = __shfl_down(smax, off, 64); int oi = __shfl_down(smaxi, off, 64);
                if (ov > smax || (ov == smax && oi < smaxi)) { smax = ov; smaxi = oi; }
            }
            if (lane == 0) { bval[wb + b * 64 + blk] = smax; bidx[wb + b * 64 + blk] = smaxi; }
        }
    }
}

__global__ void k_fin(const float* __restrict__ wpart, const float* __restrict__ sspart,
                      float* __restrict__ vec_out, int iter) {
    int b = blockIdx.x, tid = threadIdx.x;  // 64 threads
    float w = 0.f;
    for (int blk = 0; blk < 64; blk++) w += wpart[(((size_t)b * 64) + blk) * 64 + tid];
    float ss = 0.f;
    for (int blk = 0; blk < 64; blk++) ss += sspart[b * 64 + blk];
    vec_out[(b * NBV + iter) * 64 + tid] = w / ss;
}

extern "C" void kernel_launch(void* const* d_in, const int* in_sizes, int n_in,
                              void* d_out, int out_size, void* d_ws, size_t ws_size,
                              hipStream_t stream) {
    const float* x = (const float*)d_in[0];          // [B,C,H,W] fp32
    const float* sc_in = (const float*)d_in[1];      // [B,N] fp32
    float* out = (float*)d_out;                      // fp32 outputs
    float* vec_out = out;                            // B*4*C
    float* sim_out = vec_out + (size_t)BB * NBV * CC;// B*4*N
    float* sel_out = sim_out + (size_t)BB * NBV * NN;// B*N

    float* ws = (float*)d_ws;
    float* xT = ws;                                  // B*N*C (268 MB)
    float* score = xT + (size_t)BB * NN * CC;        // B*N
    float* bval = score + (size_t)BB * NN;           // 2*B64
    int* bidx = (int*)(bval + 2 * B64);              // 2*B64
    float* wpart = bval + 4 * B64;                   // B*64*64
    float* sspart = wpart + (size_t)BB * 64 * 64;    // B*64

    k_argmax1<<<dim3(64, BB), 256, 0, stream>>>(sc_in, bval, bidx, sel_out);
    k_xpose<<<dim3(1024, BB), 256, 0, stream>>>(x, xT);
    for (int it = 0; it < NBV; it++) {
        const float* s_in = (it == 0) ? sc_in : score;
        k_iter<<<dim3(64, BB), 256, 0, stream>>>(xT, x, s_in, score, bval, bidx,
                                                 wpart, sspart, sim_out, it);
        k_fin<<<dim3(BB), 64, 0, stream>>>(wpart, sspart, vec_out, it);
    }
}